// Round 3
// baseline (47.413 us; speedup 1.0000x reference)
//
#include <hip/hip_runtime.h>
#include <math.h>

#define HW 4096
#define NCH 4
#define TPB 256
#define ROWS_PER_BLOCK 16                      // 4 waves x 4 rows/wave
#define BLOCKS_PER_CH (HW / ROWS_PER_BLOCK)    // 256
#define NBLOCKS (NCH * BLOCKS_PER_CH)          // 1024
#define KNN 5

// digamma for x >= 1 (positive integers as floats).
// Shift-up recurrence to x >= 6, then asymptotic series. ~1e-7 abs error.
__device__ __forceinline__ float digammaf_dev(float x) {
    float r = 0.f;
    while (x < 6.f) { r -= 1.f / x; x += 1.f; }
    float f = 1.f / x, f2 = f * f;
    return logf(x) - 0.5f * f
         - f2 * (1.f / 12.f - f2 * (1.f / 120.f - f2 * (1.f / 252.f))) + r;
}

// Insert d into ascending sorted 6-list (drop the max).
// s0' = min(s0,d); si' = med3(s[i-1], s[i], d) -- 6 independent v_med3_f32.
__device__ __forceinline__ void insert6(float (&s)[6], float d) {
    float n0 = fminf(s[0], d);
    float n1 = __builtin_amdgcn_fmed3f(s[0], s[1], d);
    float n2 = __builtin_amdgcn_fmed3f(s[1], s[2], d);
    float n3 = __builtin_amdgcn_fmed3f(s[2], s[3], d);
    float n4 = __builtin_amdgcn_fmed3f(s[3], s[4], d);
    float n5 = __builtin_amdgcn_fmed3f(s[4], s[5], d);
    s[0] = n0; s[1] = n1; s[2] = n2; s[3] = n3; s[4] = n4; s[5] = n5;
}

__global__ __launch_bounds__(TPB) void knnmi_rows(const float* __restrict__ x,
                                                  const float* __restrict__ y,
                                                  float* __restrict__ ws) {
    __shared__ float2 sxy[HW];                 // exactly 32 KB

    const int c  = blockIdx.x / BLOCKS_PER_CH;   // channel 0..3
    const int rb = blockIdx.x % BLOCKS_PER_CH;   // row-block within channel

    const float* xc = x + c * HW;
    const float* yc = y + c * HW;

    // Stage interleaved {x,y} via float4 loads + b128 LDS writes.
    for (int i = threadIdx.x; i < HW / 4; i += TPB) {
        float4 xv = ((const float4*)xc)[i];
        float4 yv = ((const float4*)yc)[i];
        ((float4*)sxy)[2 * i]     = make_float4(xv.x, yv.x, xv.y, yv.y);
        ((float4*)sxy)[2 * i + 1] = make_float4(xv.z, yv.z, xv.w, yv.w);
    }
    __syncthreads();

    const int wv    = threadIdx.x >> 6;          // wave 0..3
    const int lane  = threadIdx.x & 63;
    const int rbase = rb * ROWS_PER_BLOCK + wv * 4;   // wave owns 4 rows

    float xr[4], yr[4];
#pragma unroll
    for (int r = 0; r < 4; ++r) {
        float2 p = sxy[rbase + r];               // uniform addr -> broadcast
        xr[r] = p.x; yr[r] = p.y;
    }

    // Pass 1: each lane scans candidates j = it*64 + lane; one ds_read_b64
    // serves all 4 rows (register tiling: 4x less LDS traffic).
    float s[4][6];
#pragma unroll
    for (int r = 0; r < 4; ++r)
#pragma unroll
        for (int q = 0; q < 6; ++q) s[r][q] = 3.4e38f;

#pragma unroll 8
    for (int it = 0; it < HW / 64; ++it) {
        float2 p = sxy[it * 64 + lane];
#pragma unroll
        for (int r = 0; r < 4; ++r) {
            float d = fmaxf(fabsf(xr[r] - p.x), fabsf(yr[r] - p.y));
            insert6(s[r], d);
        }
    }

    // Butterfly merge of 64 per-lane sorted 6-lists (per row).
#pragma unroll
    for (int m = 1; m < 64; m <<= 1) {
#pragma unroll
        for (int r = 0; r < 4; ++r) {
            float o[6];
#pragma unroll
            for (int q = 0; q < 6; ++q) o[q] = __shfl_xor(s[r][q], m);
#pragma unroll
            for (int q = 0; q < 6; ++q) insert6(s[r], o[q]);
        }
    }

    float eps[4];
#pragma unroll
    for (int r = 0; r < 4; ++r) eps[r] = s[r][5];  // (k+1)-th smallest, k=5

    // Pass 2: strict-< marginal counts (self included, as in ref).
    int nx[4] = {0, 0, 0, 0}, ny[4] = {0, 0, 0, 0};
#pragma unroll 8
    for (int it = 0; it < HW / 64; ++it) {
        float2 p = sxy[it * 64 + lane];
#pragma unroll
        for (int r = 0; r < 4; ++r) {
            nx[r] += (fabsf(xr[r] - p.x) < eps[r]);
            ny[r] += (fabsf(yr[r] - p.y) < eps[r]);
        }
    }

    // Cross-lane count reduce: pack (nx,ny) per row, 4 butterflies.
    int pk[4];
#pragma unroll
    for (int r = 0; r < 4; ++r) pk[r] = (nx[r] << 16) | ny[r];  // sums <= 4096
#pragma unroll
    for (int m = 1; m < 64; m <<= 1)
#pragma unroll
        for (int r = 0; r < 4; ++r) pk[r] += __shfl_xor(pk[r], m);

    if (lane == 0) {
        float v = 0.f;
#pragma unroll
        for (int r = 0; r < 4; ++r)
            v += digammaf_dev((float)(pk[r] >> 16))
               + digammaf_dev((float)(pk[r] & 0xffff));
        ws[blockIdx.x * 4 + wv] = v;             // per-wave partial
    }
}

__global__ void knnmi_final(const float* __restrict__ ws, float* __restrict__ out) {
    const int w    = threadIdx.x >> 6;    // wave = channel
    const int lane = threadIdx.x & 63;
    const int n    = BLOCKS_PER_CH * 4;   // 1024 partials per channel
    float sum = 0.f;
    for (int i = lane; i < n; i += 64) sum += ws[w * n + i];
#pragma unroll
    for (int m = 32; m; m >>= 1) sum += __shfl_xor(sum, m);
    if (lane == 0) {
        float mi = digammaf_dev((float)KNN) + digammaf_dev((float)HW)
                 - sum / (float)HW;
        out[w] = fmaxf(mi, 0.f);
    }
}

extern "C" void kernel_launch(void* const* d_in, const int* in_sizes, int n_in,
                              void* d_out, int out_size, void* d_ws, size_t ws_size,
                              hipStream_t stream) {
    const float* x = (const float*)d_in[0];
    const float* y = (const float*)d_in[1];
    float* out = (float*)d_out;
    float* ws  = (float*)d_ws;   // NBLOCKS*4 floats, fully rewritten every call

    knnmi_rows<<<NBLOCKS, TPB, 0, stream>>>(x, y, ws);
    knnmi_final<<<1, NCH * 64, 0, stream>>>(ws, out);
}